// Round 9
// baseline (877.841 us; speedup 1.0000x reference)
//
#include <hip/hip_runtime.h>
#include <cstddef>

// NLM: h=7/255, template 7x7 (TH=3), search 21x21 (SH=10), reflect padding.
// Tile 32x32/block, 256 threads, software-pipelined disjoint wave roles,
// double-buffered vsh, ONE barrier per offset. Structure = R9 (876us).
// R10 = R9 + PARITY ROLE SWAP (isolated from R7's fp16 confound):
//   Blocks with (bx^by)&1==1 assign Bv to tid 142..255 and C to tid 0..127.
//   Wave slots map to SIMDs by index, so without the swap every SIMD hosts
//   only one role (Bv SIMDs saturated ~248 cy/slot, C SIMDs half-idle after
//   R9's skip — measured VALUBusy 73.7%). Mixing roles across co-resident
//   blocks balances per-SIMD issue to ~186 cy/slot.
// R9 exact exp-block skip kept: w = exp2(h*K) underflows to +0.0 for
//   h > 3.84; wave-uniform ballot on min(h0..h7) > 3.95 skips the whole
//   {8 reads, 8 mul, 8 exp2, 8 fma, 8 add} block bit-exactly.
// Lessons kept: no unrolling of offset loops (R2); scalar 114-lane Bv, never
// 57-lane packed (R5/R6: starves SIMDs); float vsh, never fp16 (R7); no
// extra LDS for barrier-halving (R8: occupancy loss > barrier gain).
// (Rounds 7-8 were container-acquire infra failures; kernel logic verified
// against R7 (parity swap ran clean) and R9 (base ran clean) — resubmit.)

constexpr int TS    = 32;
constexpr int XSTR  = 61;            // odd -> benign bank aliasing
constexpr int XROWS = 59;            // image rows gy0-13 .. gy0+45
constexpr int XSZ   = XROWS * XSTR;  // 3599
constexpr int VSTR  = 42;            // even (float2-aligned), 42%8!=0
constexpr int VROWS = 33;            // 32 + 1 junk row (group-2 uniform writes)
constexpr int VS_SZ = VROWS * VSTR;  // 1386 per buffer

__device__ __forceinline__ int refl(int i, int n) {
    i = (i < 0) ? -i : i;
    return (i >= n) ? (2 * n - 2 - i) : i;
}

template<bool FAST>
__device__ __forceinline__ void nlm_body(const float* __restrict__ img,
                                         float* __restrict__ out,
                                         int H, int W, int gx0, int gy0,
                                         float* __restrict__ xs,
                                         float* __restrict__ vsh,
                                         int tid, int parity)
{
    // ---- load xs (clip to [0,1], reflect indexing) ----
    for (int e = tid; e < XSZ; e += 256) {
        int i = e / XSTR, j = e - i * XSTR;
        int jj = (j > 57) ? 57 : j;  // cols 58..60: stride pad (never read)
        int gy = refl(gy0 - 13 + i, H);
        int gx = refl(gx0 - 13 + jj, W);
        float v = img[(size_t)gy * W + gx];
        xs[e] = fminf(fmaxf(v, 0.0f), 1.0f);
    }
    __syncthreads();

    // ---- Bv setup: 114 lanes = 38 cols x 3 row-groups (11 rows, 17 q's) ----
    const int  bvt = parity ? (tid - 142) : tid;   // swap: Bv on top waves
    const bool bv  = ((unsigned)bvt < 114u);
    float u[17];
    int   aB = 0;                    // FAST: single address, +i*XSTR rows
    int   aS[17];                    // EDGE: per-row reflected addresses
    int   wb = 0;
    {
        int t  = bv ? bvt : 0;
        int g  = t / 38;
        int cc = t - g * 38;
        int r  = g * 11;
        int mxm10 = refl(gx0 + cc - 3, W) - gx0 + 3;
        if constexpr (FAST) {
            aB = r * XSTR + mxm10;
#pragma unroll
            for (int i = 0; i < 17; ++i)
                u[i] = xs[(r + i + 10) * XSTR + mxm10 + 10];
        } else {
#pragma unroll
            for (int i = 0; i < 17; ++i) {
                int my = refl(gy0 + r + i - 3, H) - gy0 + 13;
                u[i]  = xs[my * XSTR + mxm10 + 10];
                aS[i] = (my - 10) * XSTR + mxm10;
            }
        }
        wb = r * VSTR + cc;
    }

    // ---- C setup: 128 lanes = 32 rows x 4 groups of 8 cols ----
    const bool cact = parity ? (tid < 128) : (tid >= 128);
    const int ct = cact ? (parity ? tid : (tid - 128)) : 0;
    const int py = ct >> 2;
    const int c8 = (ct & 3) * 8;
    const int vb = py * VSTR + c8;              // float2-aligned (even)
    int svC = (py + 3) * XSTR + (c8 + 3);       // row base, advances per oy

    int oxB = 0;                                 // uniform ox state machines
    int oxC = 0;

    float ws[8], ac[8];
#pragma unroll
    for (int k = 0; k < 8; ++k) { ws[k] = 0.f; ac[k] = 0.f; }
    // w = exp(-mean49(d)/H2) = exp2(K * sum49(d))
    const float K = -(65025.0f / 2401.0f) * 1.4426950408889634f;  // ~ -39.07
    const float HSKIP = 3.95f;  // h > 3.95 => h*K <= -154 => exp2 == +0.0f

    auto bv_step = [&](int buf) {
        if (bv) {
            float* vo = vsh + buf * VS_SZ + wb;
            float q[17];
            if constexpr (FAST) {
#pragma unroll
                for (int i = 0; i < 17; ++i)
                    q[i] = xs[aB + i * XSTR];
            } else {
#pragma unroll
                for (int i = 0; i < 17; ++i)
                    q[i] = xs[aS[i]];
            }
#pragma unroll
            for (int i = 0; i < 17; ++i) {
                float d = u[i] - q[i];
                q[i] = d * d;
            }
            float s[11];
            s[0] = ((q[0] + q[1]) + (q[2] + q[3])) + ((q[4] + q[5]) + q[6]);
#pragma unroll
            for (int k = 1; k < 11; ++k)
                s[k] = s[k - 1] + (q[k + 6] - q[k - 1]);
#pragma unroll
            for (int k = 0; k < 11; ++k)
                vo[k * VSTR] = s[k];   // group-2 row 32 = junk, never read
            if constexpr (FAST) {
                aB += (oxB == 20) ? (XSTR - 20) : 1;
            } else {
                int step = (oxB == 20) ? (XSTR - 20) : 1;
#pragma unroll
                for (int i = 0; i < 17; ++i) aS[i] += step;
            }
        }
        oxB = (oxB == 20) ? 0 : (oxB + 1);
    };

    auto c_step = [&](int buf) {
        if (cact) {
            const float2* vp =
                reinterpret_cast<const float2*>(vsh + buf * VS_SZ + vb);
            float2 tA = vp[0], tB = vp[1], tC = vp[2], tD = vp[3];
            float2 tE = vp[4], tF = vp[5], tG = vp[6];
            float h0 = ((tA.x + tA.y) + (tB.x + tB.y)) + ((tC.x + tC.y) + tD.x);
            float h1 = h0 - tA.x + tD.y;
            float h2 = h1 - tA.y + tE.x;
            float h3 = h2 - tB.x + tE.y;
            float h4 = h3 - tB.y + tF.x;
            float h5 = h4 - tC.x + tF.y;
            float h6 = h5 - tC.y + tG.x;
            float h7 = h6 - tD.x + tG.y;
            float m = fminf(fminf(fminf(h0, h1), fminf(h2, h3)),
                            fminf(fminf(h4, h5), fminf(h6, h7)));
            if (__builtin_expect(__ballot(m <= HSKIP) != 0ull, 0)) {
                const int sp = svC + oxC;
                float x0 = xs[sp],     x1 = xs[sp + 1];
                float x2 = xs[sp + 2], x3 = xs[sp + 3];
                float x4 = xs[sp + 4], x5 = xs[sp + 5];
                float x6 = xs[sp + 6], x7 = xs[sp + 7];
                float w;
                w = __builtin_amdgcn_exp2f(h0 * K); ws[0] += w; ac[0] = fmaf(w, x0, ac[0]);
                w = __builtin_amdgcn_exp2f(h1 * K); ws[1] += w; ac[1] = fmaf(w, x1, ac[1]);
                w = __builtin_amdgcn_exp2f(h2 * K); ws[2] += w; ac[2] = fmaf(w, x2, ac[2]);
                w = __builtin_amdgcn_exp2f(h3 * K); ws[3] += w; ac[3] = fmaf(w, x3, ac[3]);
                w = __builtin_amdgcn_exp2f(h4 * K); ws[4] += w; ac[4] = fmaf(w, x4, ac[4]);
                w = __builtin_amdgcn_exp2f(h5 * K); ws[5] += w; ac[5] = fmaf(w, x5, ac[5]);
                w = __builtin_amdgcn_exp2f(h6 * K); ws[6] += w; ac[6] = fmaf(w, x6, ac[6]);
                w = __builtin_amdgcn_exp2f(h7 * K); ws[7] += w; ac[7] = fmaf(w, x7, ac[7]);
            }
            // else: all 8 weights are exactly +0.0f for every lane -> no-op.
        }
        if (oxC == 20) { oxC = 0; svC += XSTR; } else { ++oxC; }
    };

    // ---- pipelined offset loop: Bv(i) || C(i-1), 1 barrier/iter ----
    bv_step(0);
    __syncthreads();
#pragma unroll 1
    for (int i = 1; i < 441; ++i) {
        bv_step(i & 1);
        c_step(1 - (i & 1));
        __syncthreads();
        // barrier fences: C's reads of buf (i-1)&1 from next iter's Bv writes
        // to that buffer, and Bv's writes of buf i&1 from next iter's C reads.
    }
    c_step(0);   // offset 440 lives in buffer 0

    if (cact) {
        float4 oA, oB;
        oA.x = fminf(fmaxf(ac[0] * __builtin_amdgcn_rcpf(ws[0]), 0.f), 1.f);
        oA.y = fminf(fmaxf(ac[1] * __builtin_amdgcn_rcpf(ws[1]), 0.f), 1.f);
        oA.z = fminf(fmaxf(ac[2] * __builtin_amdgcn_rcpf(ws[2]), 0.f), 1.f);
        oA.w = fminf(fmaxf(ac[3] * __builtin_amdgcn_rcpf(ws[3]), 0.f), 1.f);
        oB.x = fminf(fmaxf(ac[4] * __builtin_amdgcn_rcpf(ws[4]), 0.f), 1.f);
        oB.y = fminf(fmaxf(ac[5] * __builtin_amdgcn_rcpf(ws[5]), 0.f), 1.f);
        oB.z = fminf(fmaxf(ac[6] * __builtin_amdgcn_rcpf(ws[6]), 0.f), 1.f);
        oB.w = fminf(fmaxf(ac[7] * __builtin_amdgcn_rcpf(ws[7]), 0.f), 1.f);
        float* op = &out[((size_t)blockIdx.z * H + (gy0 + py)) * W + (gx0 + c8)];
        *reinterpret_cast<float4*>(op)     = oA;
        *reinterpret_cast<float4*>(op + 4) = oB;
    }
}

__global__ __launch_bounds__(256)
void nlm_kernel(const float* __restrict__ img_all, float* __restrict__ out,
                int H, int W) {
    __shared__ __align__(16) float xs[XSZ];
    __shared__ __align__(16) float vsh[2 * VS_SZ];
    const int tid = threadIdx.x;
    const int gx0 = blockIdx.x * TS;
    const int gy0 = blockIdx.y * TS;
    const int parity = (blockIdx.x ^ blockIdx.y) & 1;
    const float* img = img_all + (size_t)blockIdx.z * H * W;
    // FAST iff no patch-center row (gy0-3..gy0+35) folds at a y-edge.
    if (gy0 - 3 >= 0 && gy0 + 35 < H)
        nlm_body<true>(img, out, H, W, gx0, gy0, xs, vsh, tid, parity);
    else
        nlm_body<false>(img, out, H, W, gx0, gy0, xs, vsh, tid, parity);
}

extern "C" void kernel_launch(void* const* d_in, const int* in_sizes, int n_in,
                              void* d_out, int out_size, void* d_ws, size_t ws_size,
                              hipStream_t stream) {
    const float* x = (const float*)d_in[0];
    float* out = (float*)d_out;
    const int H = 1024, W = 1024;
    const int B = in_sizes[0] / (H * W);
    dim3 grid(W / TS, H / TS, B);
    nlm_kernel<<<grid, dim3(256), 0, stream>>>(x, out, H, W);
}